// Round 9
// baseline (2821.544 us; speedup 1.0000x reference)
//
#include <hip/hip_runtime.h>
#include <hip/hip_bf16.h>

// RNNClassifier: B=64, T=2048, V=50000, E=256, H=256, O=16
// K0: W_ih/W_hh fp32 -> fp16 once into d_ws.
// K1 (MFMA f16): xh16[B*T][H] = fp16( emb[x] @ W_ih^T + b_ih + b_hh ).
// K2 (MFMA f16): scan. 4 WGs x 16 chains x 4 waves (1 wave/SIMD).
//   = R5 structure (full 16 B-columns, 32 MFMA/wave/step, 1 lgkm barrier)
//   + R6's chunk-relay prefetch (kills R5's per-step vmcnt stall)
//   + per-mt interleave (mt's tanh/write issued under mt+1's MFMA pipe time)
//   Per-CU step floor: 128 MFMA x 16384 FLOP / 4069 FLOP/cyc = 516 cyc.

#define B_  64
#define T_  2048
#define E_  256
#define H_  256
#define O_  16
#define H2_ 128
#define CH  16    // chains per WG
#define HP  264   // padded per-chain h stride in halves (528 B)

typedef _Float16 f16x4 __attribute__((ext_vector_type(4)));
typedef _Float16 f16x8 __attribute__((ext_vector_type(8)));
typedef float    f32x4 __attribute__((ext_vector_type(4)));

// Barrier without __syncthreads()'s vmcnt(0) drain. Safe: in-loop cross-wave
// communication is LDS-only.
#define LDS_BARRIER() asm volatile("s_waitcnt lgkmcnt(0)\n\ts_barrier" ::: "memory")

__device__ __forceinline__ float tanh_fast(float x) {
  const float e = __expf(2.0f * x);
  return fmaf(-2.0f, __builtin_amdgcn_rcpf(e + 1.0f), 1.0f);
}

// ---------------------------------------------------------------------------
__global__ __launch_bounds__(256) void k0_cvt(
    const float* __restrict__ W_ih, const float* __restrict__ W_hh,
    _Float16* __restrict__ Wih16, _Float16* __restrict__ Whh16) {
  const int i = (blockIdx.x * 256 + threadIdx.x) * 4;
  if (i < H_ * E_) {
    float4 a = *(const float4*)&W_ih[i];
    float4 b = *(const float4*)&W_hh[i];
    f16x4 ah, bh;
    ah[0]=(_Float16)a.x; ah[1]=(_Float16)a.y; ah[2]=(_Float16)a.z; ah[3]=(_Float16)a.w;
    bh[0]=(_Float16)b.x; bh[1]=(_Float16)b.y; bh[2]=(_Float16)b.z; bh[3]=(_Float16)b.w;
    *(f16x4*)&Wih16[i] = ah;
    *(f16x4*)&Whh16[i] = bh;
  }
}

// ---------------------------------------------------------------------------
// K1: gathered GEMM via MFMA (unchanged from R6).
// ---------------------------------------------------------------------------
__global__ __launch_bounds__(256) void k1_xh(
    const int* __restrict__ x, const float* __restrict__ emb,
    const _Float16* __restrict__ Wih16, const float* __restrict__ b_ih,
    const float* __restrict__ b_hh, _Float16* __restrict__ xh) {
  __shared__ _Float16 A16[64][264];
  const int tid  = threadIdx.x;
  const int w    = tid >> 6;
  const int lane = tid & 63;
  const int nl   = lane & 15;
  const int koff = (lane >> 4) << 3;
  const long r0  = (long)blockIdx.x * 64;

  {
    const int c4 = lane << 2;
#pragma unroll
    for (int it = 0; it < 16; ++it) {
      const int row = (it << 2) + w;
      const long tok = x[r0 + row];
      const float4 v = *(const float4*)&emb[tok * E_ + c4];
      f16x4 hv;
      hv[0] = (_Float16)v.x; hv[1] = (_Float16)v.y;
      hv[2] = (_Float16)v.z; hv[3] = (_Float16)v.w;
      *(f16x4*)&A16[row][c4] = hv;
    }
  }

  f16x8 bfr[4][8];
#pragma unroll
  for (int nt = 0; nt < 4; ++nt) {
    const int n = (w << 6) + (nt << 4) + nl;
#pragma unroll
    for (int kt = 0; kt < 8; ++kt)
      bfr[nt][kt] = *(const f16x8*)&Wih16[n * E_ + (kt << 5) + koff];
  }
  __syncthreads();

  f32x4 acc[4][4];
#pragma unroll
  for (int mt = 0; mt < 4; ++mt)
#pragma unroll
    for (int nt = 0; nt < 4; ++nt) acc[mt][nt] = (f32x4){};

#pragma unroll
  for (int mt = 0; mt < 4; ++mt) {
#pragma unroll
    for (int kt = 0; kt < 8; ++kt) {
      const f16x8 a = *(const f16x8*)&A16[(mt << 4) + nl][(kt << 5) + koff];
#pragma unroll
      for (int nt = 0; nt < 4; ++nt)
        acc[mt][nt] = __builtin_amdgcn_mfma_f32_16x16x32_f16(a, bfr[nt][kt], acc[mt][nt], 0, 0, 0);
    }
  }
  __syncthreads();

  {
    const int rsub = (lane >> 4) << 2;
#pragma unroll
    for (int nt = 0; nt < 4; ++nt) {
      const int n = (w << 6) + (nt << 4) + nl;
      const float bias = b_ih[n] + b_hh[n];
#pragma unroll
      for (int mt = 0; mt < 4; ++mt)
#pragma unroll
        for (int j = 0; j < 4; ++j)
          A16[(mt << 4) + rsub + j][n] = (_Float16)(acc[mt][nt][j] + bias);
    }
  }
  __syncthreads();

  {
#pragma unroll
    for (int i = 0; i < 8; ++i) {
      const int row = (w << 4) + (i << 1) + (lane >> 5);
      const int col = (lane & 31) << 3;
      *(f16x8*)&xh[(r0 + row) * H_ + col] = *(const f16x8*)&A16[row][col];
    }
  }
}

// ---------------------------------------------------------------------------
// K2: 16-chain scan, 4 waves. chain = nl; wave w owns rows [64w,64w+64)
// (4 m-tiles); C rows (w<<6)+(mt<<4)+4*quad+j, col nl. One barrier/step.
// ---------------------------------------------------------------------------
__global__ __launch_bounds__(256, 1) void k2_rnn(
    const _Float16* __restrict__ xh, const _Float16* __restrict__ Whh16,
    const float* __restrict__ fc1_w, const float* __restrict__ fc1_b,
    const float* __restrict__ fc2_w, const float* __restrict__ fc2_b,
    float* __restrict__ out) {
  __shared__ _Float16 h16[2][CH][HP];
  __shared__ float hid_s[CH][H2_ + 4];

  const int tid  = threadIdx.x;
  const int w    = tid >> 6;               // wave 0..3
  const int lane = tid & 63;
  const int nl   = lane & 15;              // chain / B-col
  const int quad = lane >> 4;
  const int koff = quad << 3;
  const int c0   = blockIdx.x * CH;

  // A-fragments: W_hh rows 64w+16mt+nl (fp16), 128 regs
  f16x8 afr[4][8];
#pragma unroll
  for (int mt = 0; mt < 4; ++mt) {
    const int i = (w << 6) + (mt << 4) + nl;
#pragma unroll
    for (int kt = 0; kt < 8; ++kt)
      afr[mt][kt] = *(const f16x8*)&Whh16[i * H_ + (kt << 5) + koff];
  }

  // h0 = 0
  {
    const int c = tid >> 4, o = (tid & 15) << 4;
    *(f16x8*)&h16[0][c][o] = (f16x8){};
    *(f16x8*)&h16[0][c][o + 8] = (f16x8){};
  }

  // xh pointer: chain c0+nl; per-mt row offset (w<<6)+(mt<<4)+(quad<<2)
  const _Float16* xb = xh + (size_t)(c0 + nl) * (T_ * H_) + (w << 6) + (quad << 2);

  // chunk-relay queues: xq = steps tt..tt+3, xn = tt+4..tt+7
  f16x4 xq[4][4], xn[4][4];
#pragma unroll
  for (int s = 0; s < 4; ++s)
#pragma unroll
    for (int mt = 0; mt < 4; ++mt) {
      xq[s][mt] = *(const f16x4*)&xb[(size_t)s * H_ + (mt << 4)];
      xn[s][mt] = *(const f16x4*)&xb[(size_t)(4 + s) * H_ + (mt << 4)];
    }
  __syncthreads();

  // STEP: per-mt MFMA chain immediately followed by that mt's tanh + write,
  // so mt+1's MFMAs (matrix pipe) overlap mt's tail (trans/VALU/LDS pipes).
#define STEP(RB, WB, S)                                                        \
  {                                                                            \
    f16x8 bfr[8];                                                              \
    _Pragma("unroll")                                                          \
    for (int kt = 0; kt < 8; ++kt)                                             \
      bfr[kt] = *(const f16x8*)&h16[RB][nl][(kt << 5) + koff];                 \
    const f32x4 zz = {};                                                       \
    _Pragma("unroll")                                                          \
    for (int mt = 0; mt < 4; ++mt) {                                           \
      f32x4 xc;                                                                \
      _Pragma("unroll")                                                        \
      for (int j = 0; j < 4; ++j) xc[j] = (float)xq[S][mt][j];                 \
      f32x4 alo = __builtin_amdgcn_mfma_f32_16x16x32_f16(afr[mt][0], bfr[0], xc, 0, 0, 0); \
      alo       = __builtin_amdgcn_mfma_f32_16x16x32_f16(afr[mt][1], bfr[1], alo, 0, 0, 0); \
      alo       = __builtin_amdgcn_mfma_f32_16x16x32_f16(afr[mt][2], bfr[2], alo, 0, 0, 0); \
      alo       = __builtin_amdgcn_mfma_f32_16x16x32_f16(afr[mt][3], bfr[3], alo, 0, 0, 0); \
      f32x4 ahi = __builtin_amdgcn_mfma_f32_16x16x32_f16(afr[mt][4], bfr[4], zz, 0, 0, 0);  \
      ahi       = __builtin_amdgcn_mfma_f32_16x16x32_f16(afr[mt][5], bfr[5], ahi, 0, 0, 0); \
      ahi       = __builtin_amdgcn_mfma_f32_16x16x32_f16(afr[mt][6], bfr[6], ahi, 0, 0, 0); \
      ahi       = __builtin_amdgcn_mfma_f32_16x16x32_f16(afr[mt][7], bfr[7], ahi, 0, 0, 0); \
      const f32x4 sm = alo + ahi;                                              \
      f16x4 o;                                                                 \
      _Pragma("unroll")                                                        \
      for (int j = 0; j < 4; ++j) o[j] = (_Float16)tanh_fast(sm[j]);           \
      *(f16x4*)&h16[WB][nl][(w << 6) + (mt << 4) + (quad << 2)] = o;           \
    }                                                                          \
    LDS_BARRIER();                                                             \
  }

  for (int tt = 0; tt < T_; tt += 4) {
    STEP(0, 1, 0)
    STEP(1, 0, 1)
    STEP(0, 1, 2)
    STEP(1, 0, 3)
    // relay rotate: vmcnt wait lands here, on loads issued 4 steps ago
#pragma unroll
    for (int s = 0; s < 4; ++s)
#pragma unroll
      for (int mt = 0; mt < 4; ++mt) xq[s][mt] = xn[s][mt];
    const int tn = tt + 8;
#pragma unroll
    for (int s = 0; s < 4; ++s) {
      const size_t ti = (size_t)((tn + s) & (T_ - 1)) * H_;  // wrap; tail unused
#pragma unroll
      for (int mt = 0; mt < 4; ++mt)
        xn[s][mt] = *(const f16x4*)&xb[ti + (mt << 4)];
    }
  }
#undef STEP

  __syncthreads();  // full drain before epilogue

  // MLP head; final h in h16[0] (T even)
#pragma unroll
  for (int p = 0; p < 8; ++p) {
    const int c = (tid >> 7) + (p << 1);
    const int o = tid & 127;
    float s = fc1_b[o];
#pragma unroll 8
    for (int k = 0; k < H_; ++k) s += fc1_w[o * H_ + k] * (float)h16[0][c][k];
    hid_s[c][o] = fmaxf(s, 0.f);
  }
  __syncthreads();
  {
    const int c = tid >> 4, o = tid & 15;
    float s = fc2_b[o];
#pragma unroll 8
    for (int k = 0; k < H2_; ++k) s += fc2_w[o * H2_ + k] * hid_s[c][k];
    out[(size_t)(c0 + c) * O_ + o] = s;
  }
}

extern "C" void kernel_launch(void* const* d_in, const int* in_sizes, int n_in,
                              void* d_out, int out_size, void* d_ws, size_t ws_size,
                              hipStream_t stream) {
  const int*   x     = (const int*)d_in[0];
  const float* emb   = (const float*)d_in[1];
  const float* W_ih  = (const float*)d_in[2];
  const float* W_hh  = (const float*)d_in[3];
  const float* b_ih  = (const float*)d_in[4];
  const float* b_hh  = (const float*)d_in[5];
  const float* fc1_w = (const float*)d_in[6];
  const float* fc1_b = (const float*)d_in[7];
  const float* fc2_w = (const float*)d_in[8];
  const float* fc2_b = (const float*)d_in[9];
  float* outp = (float*)d_out;

  _Float16* xh16  = (_Float16*)d_ws;                    // 64 MiB
  _Float16* Wih16 = xh16 + (size_t)B_ * T_ * H_;        // 128 KiB
  _Float16* Whh16 = Wih16 + (size_t)H_ * E_;            // 128 KiB

  k0_cvt<<<dim3(H_ * E_ / 1024), dim3(256), 0, stream>>>(W_ih, W_hh, Wih16, Whh16);
  k1_xh<<<dim3(B_ * T_ / 64), dim3(256), 0, stream>>>(x, emb, Wih16, b_ih, b_hh, xh16);
  k2_rnn<<<dim3(B_ / CH), dim3(256), 0, stream>>>(xh16, Whh16, fc1_w, fc1_b, fc2_w, fc2_b, outp);
}

// Round 10
// 1568.543 us; speedup vs baseline: 1.7988x; 1.7988x over previous
//
#include <hip/hip_runtime.h>
#include <hip/hip_bf16.h>

// RNNClassifier: B=64, T=2048, V=50000, E=256, H=256, O=16
// K0: W_ih/W_hh fp32 -> fp16 once into d_ws.
// K1 (MFMA f16): xh16[B*T][H] = fp16( emb[x] @ W_ih^T + b_ih + b_hh ).
// K2 (MFMA f16): scan. 32 WGs x 2 chains x 4 waves. Two-phase step (R6
//   champion structure): ph1 = 32 MFMA/wave -> f32 sums to LDS; ph2 = all
//   256 thr, 2 tanh each -> h16. Two lgkm-only barriers/step, chunk-relay
//   xh prefetch. CH=2 cuts LDS B-frag bandwidth (8-lane broadcasts),
//   tanh/thread, and per-CU xh traffic vs R6's CH=4.

#define B_  64
#define T_  2048
#define E_  256
#define H_  256
#define O_  16
#define H2_ 128
#define CH  2     // chains per WG
#define HP  264   // padded h stride (halves)

typedef _Float16 f16x2 __attribute__((ext_vector_type(2)));
typedef _Float16 f16x4 __attribute__((ext_vector_type(4)));
typedef _Float16 f16x8 __attribute__((ext_vector_type(8)));
typedef float    f32x2 __attribute__((ext_vector_type(2)));
typedef float    f32x4 __attribute__((ext_vector_type(4)));

// Barrier without __syncthreads()'s vmcnt(0) drain. Safe: in-loop cross-wave
// communication is LDS-only.
#define LDS_BARRIER() asm volatile("s_waitcnt lgkmcnt(0)\n\ts_barrier" ::: "memory")

__device__ __forceinline__ float tanh_fast(float x) {
  const float e = __expf(2.0f * x);
  return fmaf(-2.0f, __builtin_amdgcn_rcpf(e + 1.0f), 1.0f);
}

// ---------------------------------------------------------------------------
__global__ __launch_bounds__(256) void k0_cvt(
    const float* __restrict__ W_ih, const float* __restrict__ W_hh,
    _Float16* __restrict__ Wih16, _Float16* __restrict__ Whh16) {
  const int i = (blockIdx.x * 256 + threadIdx.x) * 4;
  if (i < H_ * E_) {
    float4 a = *(const float4*)&W_ih[i];
    float4 b = *(const float4*)&W_hh[i];
    f16x4 ah, bh;
    ah[0]=(_Float16)a.x; ah[1]=(_Float16)a.y; ah[2]=(_Float16)a.z; ah[3]=(_Float16)a.w;
    bh[0]=(_Float16)b.x; bh[1]=(_Float16)b.y; bh[2]=(_Float16)b.z; bh[3]=(_Float16)b.w;
    *(f16x4*)&Wih16[i] = ah;
    *(f16x4*)&Whh16[i] = bh;
  }
}

// ---------------------------------------------------------------------------
// K1: gathered GEMM via MFMA (unchanged from R6).
// ---------------------------------------------------------------------------
__global__ __launch_bounds__(256) void k1_xh(
    const int* __restrict__ x, const float* __restrict__ emb,
    const _Float16* __restrict__ Wih16, const float* __restrict__ b_ih,
    const float* __restrict__ b_hh, _Float16* __restrict__ xh) {
  __shared__ _Float16 A16[64][264];
  const int tid  = threadIdx.x;
  const int w    = tid >> 6;
  const int lane = tid & 63;
  const int nl   = lane & 15;
  const int koff = (lane >> 4) << 3;
  const long r0  = (long)blockIdx.x * 64;

  {
    const int c4 = lane << 2;
#pragma unroll
    for (int it = 0; it < 16; ++it) {
      const int row = (it << 2) + w;
      const long tok = x[r0 + row];
      const float4 v = *(const float4*)&emb[tok * E_ + c4];
      f16x4 hv;
      hv[0] = (_Float16)v.x; hv[1] = (_Float16)v.y;
      hv[2] = (_Float16)v.z; hv[3] = (_Float16)v.w;
      *(f16x4*)&A16[row][c4] = hv;
    }
  }

  f16x8 bfr[4][8];
#pragma unroll
  for (int nt = 0; nt < 4; ++nt) {
    const int n = (w << 6) + (nt << 4) + nl;
#pragma unroll
    for (int kt = 0; kt < 8; ++kt)
      bfr[nt][kt] = *(const f16x8*)&Wih16[n * E_ + (kt << 5) + koff];
  }
  __syncthreads();

  f32x4 acc[4][4];
#pragma unroll
  for (int mt = 0; mt < 4; ++mt)
#pragma unroll
    for (int nt = 0; nt < 4; ++nt) acc[mt][nt] = (f32x4){};

#pragma unroll
  for (int mt = 0; mt < 4; ++mt) {
#pragma unroll
    for (int kt = 0; kt < 8; ++kt) {
      const f16x8 a = *(const f16x8*)&A16[(mt << 4) + nl][(kt << 5) + koff];
#pragma unroll
      for (int nt = 0; nt < 4; ++nt)
        acc[mt][nt] = __builtin_amdgcn_mfma_f32_16x16x32_f16(a, bfr[nt][kt], acc[mt][nt], 0, 0, 0);
    }
  }
  __syncthreads();

  {
    const int rsub = (lane >> 4) << 2;
#pragma unroll
    for (int nt = 0; nt < 4; ++nt) {
      const int n = (w << 6) + (nt << 4) + nl;
      const float bias = b_ih[n] + b_hh[n];
#pragma unroll
      for (int mt = 0; mt < 4; ++mt)
#pragma unroll
        for (int j = 0; j < 4; ++j)
          A16[(mt << 4) + rsub + j][n] = (_Float16)(acc[mt][nt][j] + bias);
    }
  }
  __syncthreads();

  {
#pragma unroll
    for (int i = 0; i < 8; ++i) {
      const int row = (w << 4) + (i << 1) + (lane >> 5);
      const int col = (lane & 31) << 3;
      *(f16x8*)&xh[(r0 + row) * H_ + col] = *(const f16x8*)&A16[row][col];
    }
  }
}

// ---------------------------------------------------------------------------
// K2: 2-chain scan, 32 WGs x 256 thr (4 waves). Ph1: wave w rows
// [64w,64w+64), B col nl = chain nl&1 (8-lane broadcast reads); writer
// lanes nl<2 store f32 sums. Ph2: thread (c=tid>>7, o2=(tid&127)*2) does
// 2 tanh. Two lgkm-only barriers/step.
// ---------------------------------------------------------------------------
__global__ __launch_bounds__(256, 1) void k2_rnn(
    const _Float16* __restrict__ xh, const _Float16* __restrict__ Whh16,
    const float* __restrict__ fc1_w, const float* __restrict__ fc1_b,
    const float* __restrict__ fc2_w, const float* __restrict__ fc2_b,
    float* __restrict__ out) {
  __shared__ _Float16 h16[2][CH][HP];   // ping-pong hidden (fp16)
  __shared__ float    sc[CH][264];      // f32 matvec sums
  __shared__ float    hid_s[CH][H2_ + 4];

  const int tid  = threadIdx.x;
  const int w    = tid >> 6;            // wave 0..3
  const int lane = tid & 63;
  const int nl   = lane & 15;
  const int quad = lane >> 4;
  const int cc   = nl & 1;              // chain for this B col
  const int koff = quad << 3;
  const int c0   = blockIdx.x * CH;
  const int pc   = tid >> 7;            // ph2 chain
  const int po   = (tid & 127) << 1;    // ph2 elements po, po+1

  // A-frags: W_hh rows 64w+16mt+nl (fp16), 128 regs (AGPR-resident ok)
  f16x8 afr[4][8];
#pragma unroll
  for (int mt = 0; mt < 4; ++mt) {
    const int i = (w << 6) + (mt << 4) + nl;
#pragma unroll
    for (int kt = 0; kt < 8; ++kt)
      afr[mt][kt] = *(const f16x8*)&Whh16[i * H_ + (kt << 5) + koff];
  }

  // h0 = 0 (2*264 = 528 halves incl pad)
  if (tid < 66) *(f16x8*)&(((_Float16*)h16[0])[tid << 3]) = (f16x8){};

  // xh stream: thread covers chain pc, elements po..po+1 of each step
  const _Float16* xb = xh + (size_t)(c0 + pc) * T_ * H_ + po;
  f16x2 xq[4], xn[4];
#pragma unroll
  for (int s = 0; s < 4; ++s) xq[s] = *(const f16x2*)&xb[(size_t)s * H_];
#pragma unroll
  for (int s = 0; s < 4; ++s) xn[s] = *(const f16x2*)&xb[(size_t)(4 + s) * H_];
  __syncthreads();

#define STEP(RB, WB, S)                                                        \
  {                                                                            \
    f16x8 bfr[8];                                                              \
    _Pragma("unroll")                                                          \
    for (int kt = 0; kt < 8; ++kt)                                             \
      bfr[kt] = *(const f16x8*)&h16[RB][cc][(kt << 5) + koff];                 \
    const f32x4 zz = {};                                                       \
    _Pragma("unroll")                                                          \
    for (int mt = 0; mt < 4; ++mt) {                                           \
      f32x4 a0 = __builtin_amdgcn_mfma_f32_16x16x32_f16(afr[mt][0], bfr[0], zz, 0, 0, 0); \
      a0       = __builtin_amdgcn_mfma_f32_16x16x32_f16(afr[mt][1], bfr[1], a0, 0, 0, 0); \
      a0       = __builtin_amdgcn_mfma_f32_16x16x32_f16(afr[mt][2], bfr[2], a0, 0, 0, 0); \
      a0       = __builtin_amdgcn_mfma_f32_16x16x32_f16(afr[mt][3], bfr[3], a0, 0, 0, 0); \
      f32x4 a1 = __builtin_amdgcn_mfma_f32_16x16x32_f16(afr[mt][4], bfr[4], zz, 0, 0, 0); \
      a1       = __builtin_amdgcn_mfma_f32_16x16x32_f16(afr[mt][5], bfr[5], a1, 0, 0, 0); \
      a1       = __builtin_amdgcn_mfma_f32_16x16x32_f16(afr[mt][6], bfr[6], a1, 0, 0, 0); \
      a1       = __builtin_amdgcn_mfma_f32_16x16x32_f16(afr[mt][7], bfr[7], a1, 0, 0, 0); \
      const f32x4 sm = a0 + a1;                                                \
      if (nl < CH)                                                             \
        *(f32x4*)&sc[nl][(w << 6) + (mt << 4) + (quad << 2)] = sm;             \
    }                                                                          \
    LDS_BARRIER();                                                             \
    {                                                                          \
      const f32x2 sv = *(const f32x2*)&sc[pc][po];                             \
      f16x2 o;                                                                 \
      o[0] = (_Float16)tanh_fast(sv[0] + (float)xq[S][0]);                     \
      o[1] = (_Float16)tanh_fast(sv[1] + (float)xq[S][1]);                     \
      *(f16x2*)&h16[WB][pc][po] = o;                                           \
    }                                                                          \
    LDS_BARRIER();                                                             \
  }

  for (int tt = 0; tt < T_; tt += 4) {
    STEP(0, 1, 0)
    STEP(1, 0, 1)
    STEP(0, 1, 2)
    STEP(1, 0, 3)
    // relay rotate: vmcnt wait lands here, on loads issued 4 steps ago
#pragma unroll
    for (int s = 0; s < 4; ++s) xq[s] = xn[s];
    const int tn = tt + 8;
#pragma unroll
    for (int s = 0; s < 4; ++s) {
      const size_t ti = (size_t)((tn + s) & (T_ - 1)) * H_;  // wrap; tail unused
      xn[s] = *(const f16x2*)&xb[ti];
    }
  }
#undef STEP

  __syncthreads();  // full drain before epilogue

  // MLP head; final h in h16[0] (T even). fc1: thread (pc, o=tid&127).
  {
    const int o = tid & 127;
    float s = fc1_b[o];
#pragma unroll 8
    for (int k = 0; k < H_; ++k) s += fc1_w[o * H_ + k] * (float)h16[0][pc][k];
    hid_s[pc][o] = fmaxf(s, 0.f);
  }
  __syncthreads();
  if (tid < CH * O_) {
    const int c = tid >> 4, o = tid & 15;
    float s = fc2_b[o];
#pragma unroll 8
    for (int k = 0; k < H2_; ++k) s += fc2_w[o * H2_ + k] * hid_s[c][k];
    out[(size_t)(c0 + c) * O_ + o] = s;
  }
}

extern "C" void kernel_launch(void* const* d_in, const int* in_sizes, int n_in,
                              void* d_out, int out_size, void* d_ws, size_t ws_size,
                              hipStream_t stream) {
  const int*   x     = (const int*)d_in[0];
  const float* emb   = (const float*)d_in[1];
  const float* W_ih  = (const float*)d_in[2];
  const float* W_hh  = (const float*)d_in[3];
  const float* b_ih  = (const float*)d_in[4];
  const float* b_hh  = (const float*)d_in[5];
  const float* fc1_w = (const float*)d_in[6];
  const float* fc1_b = (const float*)d_in[7];
  const float* fc2_w = (const float*)d_in[8];
  const float* fc2_b = (const float*)d_in[9];
  float* outp = (float*)d_out;

  _Float16* xh16  = (_Float16*)d_ws;                    // 64 MiB
  _Float16* Wih16 = xh16 + (size_t)B_ * T_ * H_;        // 128 KiB
  _Float16* Whh16 = Wih16 + (size_t)H_ * E_;            // 128 KiB

  k0_cvt<<<dim3(H_ * E_ / 1024), dim3(256), 0, stream>>>(W_ih, W_hh, Wih16, Whh16);
  k1_xh<<<dim3(B_ * T_ / 64), dim3(256), 0, stream>>>(x, emb, Wih16, b_ih, b_hh, xh16);
  k2_rnn<<<dim3(B_ / CH), dim3(256), 0, stream>>>(xh16, Whh16, fc1_w, fc1_b, fc2_w, fc2_b, outp);
}

// Round 11
// 1375.708 us; speedup vs baseline: 2.0510x; 1.1402x over previous
//
#include <hip/hip_runtime.h>
#include <hip/hip_bf16.h>

// RNNClassifier: B=64, T=2048, V=50000, E=256, H=256, O=16
// K0: W_ih/W_hh fp32 -> fp16 once into d_ws.
// K1 (MFMA f16): xh16[B*T][H] = fp16( emb[x] @ W_ih^T + b_ih + b_hh ).
// K2 (MFMA f16): scan. 32 WGs x 2 chains x 4 waves. SINGLE-PHASE step:
//   with CH=2 and B col n loaded from chain n&1, ALL 16 MFMA C-columns are
//   valid (8x redundant) -> every lane holds the full f32 sums in registers.
//   No sc scratch, no phase2, ONE lgkm barrier/step. Lane nl handles m-tile
//   (nl>>1)&3 (4-way select) -> 4 tanh/lane; lanes nl<8 write h16 directly.
//   xh per-lane slice via chunk-relay (addresses duplicate -> coalesced).

#define B_  64
#define T_  2048
#define E_  256
#define H_  256
#define O_  16
#define H2_ 128
#define CH  2     // chains per WG
#define HP  264   // padded h stride (halves)

typedef _Float16 f16x4 __attribute__((ext_vector_type(4)));
typedef _Float16 f16x8 __attribute__((ext_vector_type(8)));
typedef float    f32x4 __attribute__((ext_vector_type(4)));

// Barrier without __syncthreads()'s vmcnt(0) drain. Safe: in-loop cross-wave
// communication is LDS-only.
#define LDS_BARRIER() asm volatile("s_waitcnt lgkmcnt(0)\n\ts_barrier" ::: "memory")

__device__ __forceinline__ float tanh_fast(float x) {
  const float e = __expf(2.0f * x);
  return fmaf(-2.0f, __builtin_amdgcn_rcpf(e + 1.0f), 1.0f);
}

// ---------------------------------------------------------------------------
__global__ __launch_bounds__(256) void k0_cvt(
    const float* __restrict__ W_ih, const float* __restrict__ W_hh,
    _Float16* __restrict__ Wih16, _Float16* __restrict__ Whh16) {
  const int i = (blockIdx.x * 256 + threadIdx.x) * 4;
  if (i < H_ * E_) {
    float4 a = *(const float4*)&W_ih[i];
    float4 b = *(const float4*)&W_hh[i];
    f16x4 ah, bh;
    ah[0]=(_Float16)a.x; ah[1]=(_Float16)a.y; ah[2]=(_Float16)a.z; ah[3]=(_Float16)a.w;
    bh[0]=(_Float16)b.x; bh[1]=(_Float16)b.y; bh[2]=(_Float16)b.z; bh[3]=(_Float16)b.w;
    *(f16x4*)&Wih16[i] = ah;
    *(f16x4*)&Whh16[i] = bh;
  }
}

// ---------------------------------------------------------------------------
// K1: gathered GEMM via MFMA (unchanged from R6).
// ---------------------------------------------------------------------------
__global__ __launch_bounds__(256) void k1_xh(
    const int* __restrict__ x, const float* __restrict__ emb,
    const _Float16* __restrict__ Wih16, const float* __restrict__ b_ih,
    const float* __restrict__ b_hh, _Float16* __restrict__ xh) {
  __shared__ _Float16 A16[64][264];
  const int tid  = threadIdx.x;
  const int w    = tid >> 6;
  const int lane = tid & 63;
  const int nl   = lane & 15;
  const int koff = (lane >> 4) << 3;
  const long r0  = (long)blockIdx.x * 64;

  {
    const int c4 = lane << 2;
#pragma unroll
    for (int it = 0; it < 16; ++it) {
      const int row = (it << 2) + w;
      const long tok = x[r0 + row];
      const float4 v = *(const float4*)&emb[tok * E_ + c4];
      f16x4 hv;
      hv[0] = (_Float16)v.x; hv[1] = (_Float16)v.y;
      hv[2] = (_Float16)v.z; hv[3] = (_Float16)v.w;
      *(f16x4*)&A16[row][c4] = hv;
    }
  }

  f16x8 bfr[4][8];
#pragma unroll
  for (int nt = 0; nt < 4; ++nt) {
    const int n = (w << 6) + (nt << 4) + nl;
#pragma unroll
    for (int kt = 0; kt < 8; ++kt)
      bfr[nt][kt] = *(const f16x8*)&Wih16[n * E_ + (kt << 5) + koff];
  }
  __syncthreads();

  f32x4 acc[4][4];
#pragma unroll
  for (int mt = 0; mt < 4; ++mt)
#pragma unroll
    for (int nt = 0; nt < 4; ++nt) acc[mt][nt] = (f32x4){};

#pragma unroll
  for (int mt = 0; mt < 4; ++mt) {
#pragma unroll
    for (int kt = 0; kt < 8; ++kt) {
      const f16x8 a = *(const f16x8*)&A16[(mt << 4) + nl][(kt << 5) + koff];
#pragma unroll
      for (int nt = 0; nt < 4; ++nt)
        acc[mt][nt] = __builtin_amdgcn_mfma_f32_16x16x32_f16(a, bfr[nt][kt], acc[mt][nt], 0, 0, 0);
    }
  }
  __syncthreads();

  {
    const int rsub = (lane >> 4) << 2;
#pragma unroll
    for (int nt = 0; nt < 4; ++nt) {
      const int n = (w << 6) + (nt << 4) + nl;
      const float bias = b_ih[n] + b_hh[n];
#pragma unroll
      for (int mt = 0; mt < 4; ++mt)
#pragma unroll
        for (int j = 0; j < 4; ++j)
          A16[(mt << 4) + rsub + j][n] = (_Float16)(acc[mt][nt][j] + bias);
    }
  }
  __syncthreads();

  {
#pragma unroll
    for (int i = 0; i < 8; ++i) {
      const int row = (w << 4) + (i << 1) + (lane >> 5);
      const int col = (lane & 31) << 3;
      *(f16x8*)&xh[(r0 + row) * H_ + col] = *(const f16x8*)&A16[row][col];
    }
  }
}

// ---------------------------------------------------------------------------
// K2: 2-chain single-phase scan, 32 WGs x 256 thr (4 waves).
// Wave w rows [64w,64w+64). Lane (quad,nl): B col nl <- chain nl&1;
// after MFMA, lane owns C rows (w<<6)+(mt<<4)+(quad<<2)+j for chain nl&1.
// Lane handles mt=(nl>>1)&3: tanh 4 vals; lanes nl<8 write h16[WB].
// ---------------------------------------------------------------------------
__global__ __launch_bounds__(256, 1) void k2_rnn(
    const _Float16* __restrict__ xh, const _Float16* __restrict__ Whh16,
    const float* __restrict__ fc1_w, const float* __restrict__ fc1_b,
    const float* __restrict__ fc2_w, const float* __restrict__ fc2_b,
    float* __restrict__ out) {
  __shared__ _Float16 h16[2][CH][HP];   // ping-pong hidden (fp16)
  __shared__ float    hid_s[CH][H2_ + 4];

  const int tid  = threadIdx.x;
  const int w    = tid >> 6;            // wave 0..3
  const int lane = tid & 63;
  const int nl   = lane & 15;
  const int quad = lane >> 4;
  const int cc   = nl & 1;              // this col's chain
  const int mts  = (nl >> 1) & 3;       // this lane's m-tile for the epilogue
  const int koff = quad << 3;
  const int rowb = (w << 6) + (mts << 4) + (quad << 2);  // 4 rows owned
  const int c0   = blockIdx.x * CH;

  // A-frags: W_hh rows 64w+16mt+nl (fp16), 128 regs
  f16x8 afr[4][8];
#pragma unroll
  for (int mt = 0; mt < 4; ++mt) {
    const int i = (w << 6) + (mt << 4) + nl;
#pragma unroll
    for (int kt = 0; kt < 8; ++kt)
      afr[mt][kt] = *(const f16x8*)&Whh16[i * H_ + (kt << 5) + koff];
  }

  // h0 = 0 (2*264 = 528 halves incl pad)
  if (tid < 66) *(f16x8*)&(((_Float16*)h16[0])[tid << 3]) = (f16x8){};

  // xh stream: chain cc, rows rowb..rowb+3 of each step (lanes nl>=8
  // duplicate nl-8's address -> coalesced, no extra traffic)
  const _Float16* xb = xh + (size_t)(c0 + cc) * T_ * H_ + rowb;
  f16x4 xq[4], xn[4];
#pragma unroll
  for (int s = 0; s < 4; ++s) xq[s] = *(const f16x4*)&xb[(size_t)s * H_];
#pragma unroll
  for (int s = 0; s < 4; ++s) xn[s] = *(const f16x4*)&xb[(size_t)(4 + s) * H_];
  __syncthreads();

#define STEP(RB, WB, S)                                                        \
  {                                                                            \
    f16x8 bfr[8];                                                              \
    _Pragma("unroll")                                                          \
    for (int kt = 0; kt < 8; ++kt)                                             \
      bfr[kt] = *(const f16x8*)&h16[RB][cc][(kt << 5) + koff];                 \
    const f32x4 zz = {};                                                       \
    f32x4 sm[4];                                                               \
    _Pragma("unroll")                                                          \
    for (int mt = 0; mt < 4; ++mt) {                                           \
      f32x4 a0 = __builtin_amdgcn_mfma_f32_16x16x32_f16(afr[mt][0], bfr[0], zz, 0, 0, 0); \
      a0       = __builtin_amdgcn_mfma_f32_16x16x32_f16(afr[mt][1], bfr[1], a0, 0, 0, 0); \
      a0       = __builtin_amdgcn_mfma_f32_16x16x32_f16(afr[mt][2], bfr[2], a0, 0, 0, 0); \
      a0       = __builtin_amdgcn_mfma_f32_16x16x32_f16(afr[mt][3], bfr[3], a0, 0, 0, 0); \
      f32x4 a1 = __builtin_amdgcn_mfma_f32_16x16x32_f16(afr[mt][4], bfr[4], zz, 0, 0, 0); \
      a1       = __builtin_amdgcn_mfma_f32_16x16x32_f16(afr[mt][5], bfr[5], a1, 0, 0, 0); \
      a1       = __builtin_amdgcn_mfma_f32_16x16x32_f16(afr[mt][6], bfr[6], a1, 0, 0, 0); \
      a1       = __builtin_amdgcn_mfma_f32_16x16x32_f16(afr[mt][7], bfr[7], a1, 0, 0, 0); \
      sm[mt] = a0 + a1;                                                        \
    }                                                                          \
    f32x4 ss = sm[0];                                                          \
    _Pragma("unroll")                                                          \
    for (int m = 1; m < 4; ++m) if (mts == m) ss = sm[m];                      \
    f16x4 o;                                                                   \
    _Pragma("unroll")                                                          \
    for (int j = 0; j < 4; ++j)                                                \
      o[j] = (_Float16)tanh_fast(ss[j] + (float)xq[S][j]);                     \
    if (nl < 8) *(f16x4*)&h16[WB][cc][rowb] = o;                               \
    LDS_BARRIER();                                                             \
  }

  for (int tt = 0; tt < T_; tt += 4) {
    STEP(0, 1, 0)
    STEP(1, 0, 1)
    STEP(0, 1, 2)
    STEP(1, 0, 3)
    // relay rotate: vmcnt wait lands here, on loads issued 4 steps ago
#pragma unroll
    for (int s = 0; s < 4; ++s) xq[s] = xn[s];
    const int tn = tt + 8;
#pragma unroll
    for (int s = 0; s < 4; ++s) {
      const size_t ti = (size_t)((tn + s) & (T_ - 1)) * H_;  // wrap; tail unused
      xn[s] = *(const f16x4*)&xb[ti];
    }
  }
#undef STEP

  __syncthreads();  // full drain before epilogue

  // MLP head; final h in h16[0] (T even). fc1: thread (c=tid>>7, o=tid&127).
  {
    const int pc = tid >> 7;
    const int o  = tid & 127;
    float s = fc1_b[o];
#pragma unroll 8
    for (int k = 0; k < H_; ++k) s += fc1_w[o * H_ + k] * (float)h16[0][pc][k];
    hid_s[pc][o] = fmaxf(s, 0.f);
  }
  __syncthreads();
  if (tid < CH * O_) {
    const int c = tid >> 4, o = tid & 15;
    float s = fc2_b[o];
#pragma unroll 8
    for (int k = 0; k < H2_; ++k) s += fc2_w[o * H2_ + k] * hid_s[c][k];
    out[(size_t)(c0 + c) * O_ + o] = s;
  }
}

extern "C" void kernel_launch(void* const* d_in, const int* in_sizes, int n_in,
                              void* d_out, int out_size, void* d_ws, size_t ws_size,
                              hipStream_t stream) {
  const int*   x     = (const int*)d_in[0];
  const float* emb   = (const float*)d_in[1];
  const float* W_ih  = (const float*)d_in[2];
  const float* W_hh  = (const float*)d_in[3];
  const float* b_ih  = (const float*)d_in[4];
  const float* b_hh  = (const float*)d_in[5];
  const float* fc1_w = (const float*)d_in[6];
  const float* fc1_b = (const float*)d_in[7];
  const float* fc2_w = (const float*)d_in[8];
  const float* fc2_b = (const float*)d_in[9];
  float* outp = (float*)d_out;

  _Float16* xh16  = (_Float16*)d_ws;                    // 64 MiB
  _Float16* Wih16 = xh16 + (size_t)B_ * T_ * H_;        // 128 KiB
  _Float16* Whh16 = Wih16 + (size_t)H_ * E_;            // 128 KiB

  k0_cvt<<<dim3(H_ * E_ / 1024), dim3(256), 0, stream>>>(W_ih, W_hh, Wih16, Whh16);
  k1_xh<<<dim3(B_ * T_ / 64), dim3(256), 0, stream>>>(x, emb, Wih16, b_ih, b_hh, xh16);
  k2_rnn<<<dim3(B_ / CH), dim3(256), 0, stream>>>(xh16, Whh16, fc1_w, fc1_b, fc2_w, fc2_b, outp);
}